// Round 2
// baseline (767.108 us; speedup 1.0000x reference)
//
#include <hip/hip_runtime.h>
#include <stdint.h>

// DBSCAN, N=16384 points in R^3, eps=0.2, minPts=10.
//
// Round-2 structure: the eps-graph is sparse (~100k edges of 134M candidate
// pairs), so do ONE triangular N^2 pass that only tests distances and appends
// edges to a compact list (LDS-buffered, one global atomicAdd per block).
// Everything downstream (degree, core, union-find, border root-min) runs over
// the edge list with high occupancy -> atomic latency fully hidden.
//
// Numerics replicate the reference EXACTLY in fp32 (validated absmax=0 in R1):
//   sq  = (x*x + y*y) + z*z                   (left-to-right)
//   dot = fma(z,z', fma(y,y', x*x'))          (BLAS k-ordered FMA chain)
//   d2  = (sq_i + sq_j) - 2.0f*dot
//   adj = d2 < 0.04f

#define N_PTS   16384
#define BLOCK   256
#define IPT     2
#define TILE    512                 // i-tile == j-tile
#define NT      (N_PTS / TILE)      // 32
#define EPS2    0.04f
#define MINPTS  10
#define ECAP    (1 << 19)           // 512K edge capacity (expected ~100k)
#define LBUF    1024                // per-block LDS edge buffer (expected ~190/tile)

__device__ __forceinline__ float dist2(float px, float py, float pz, float sqi, float4 q) {
    float dot = __fmaf_rn(pz, q.z, __fmaf_rn(py, q.y, __fmul_rn(px, q.x)));
    return __fsub_rn(__fadd_rn(sqi, q.w), __fmul_rn(2.0f, dot));
}

// ---- lock-free union-find (device scope; hook larger root under smaller) ----
// Min index of a component is never hooked under anyone => final root == min
// core index == reference's min-label fixpoint.
__device__ __forceinline__ int uf_find(int* parent, int x) {
    int p = __hip_atomic_load(&parent[x], __ATOMIC_RELAXED, __HIP_MEMORY_SCOPE_AGENT);
    while (p != x) {
        int gp = __hip_atomic_load(&parent[p], __ATOMIC_RELAXED, __HIP_MEMORY_SCOPE_AGENT);
        if (gp != p)
            __hip_atomic_store(&parent[x], gp, __ATOMIC_RELAXED, __HIP_MEMORY_SCOPE_AGENT);
        x = p; p = gp;
    }
    return x;
}

__device__ __forceinline__ void uf_union(int* parent, int a, int b) {
    while (true) {
        a = uf_find(parent, a);
        b = uf_find(parent, b);
        if (a == b) return;
        if (a > b) { int t = a; a = b; b = t; }
        int expected = b;
        if (__hip_atomic_compare_exchange_strong(&parent[b], &expected, a,
                __ATOMIC_RELAXED, __ATOMIC_RELAXED, __HIP_MEMORY_SCOPE_AGENT))
            return;
    }
}

// ---------------------------------------------------------------------------
__global__ void k_init(const float* __restrict__ pts, float* __restrict__ sq,
                       int* __restrict__ deg, int* __restrict__ parent,
                       int* __restrict__ gcnt) {
    int i = blockIdx.x * BLOCK + threadIdx.x;
    float x = pts[3 * i], y = pts[3 * i + 1], z = pts[3 * i + 2];
    sq[i] = __fadd_rn(__fadd_rn(__fmul_rn(x, x), __fmul_rn(y, y)), __fmul_rn(z, z));
    deg[i] = 1;        // self-neighbor (d=0 < eps)
    parent[i] = i;
    if (i == 0) *gcnt = 0;
}

// Triangular N^2 pass: detect eps-pairs (j < i), append packed (i<<14|j).
__global__ void k_edges(const float* __restrict__ pts, const float* __restrict__ sq,
                        uint32_t* __restrict__ edges, int* __restrict__ gcnt) {
    const int bi = blockIdx.x, bj = blockIdx.y;
    if (bj > bi) return;                       // above diagonal: nothing to do
    __shared__ float4 sj[TILE];
    __shared__ uint32_t lbuf[LBUF];
    __shared__ int lcnt, lbase;
    const int tid = threadIdx.x;
    if (tid == 0) lcnt = 0;
    const int i0 = bi * TILE, j0 = bj * TILE;
    for (int idx = tid; idx < TILE; idx += BLOCK) {
        int j = j0 + idx;
        sj[idx] = make_float4(pts[3 * j], pts[3 * j + 1], pts[3 * j + 2], sq[j]);
    }
    __syncthreads();
    float px[IPT], py[IPT], pz[IPT], sqi[IPT];
    int ii[IPT];
#pragma unroll
    for (int k = 0; k < IPT; ++k) {
        int i = i0 + k * BLOCK + tid;
        ii[k] = i;
        px[k] = pts[3 * i]; py[k] = pts[3 * i + 1]; pz[k] = pts[3 * i + 2];
        sqi[k] = sq[i];
    }
#pragma unroll 4
    for (int j = 0; j < TILE; ++j) {
        float4 q = sj[j];
        int jg = j0 + j;
#pragma unroll
        for (int k = 0; k < IPT; ++k) {
            float d2 = dist2(px[k], py[k], pz[k], sqi[k], q);
            if (d2 < EPS2 && jg < ii[k]) {
                int s = atomicAdd(&lcnt, 1);            // LDS atomic: cheap
                if (s < LBUF) lbuf[s] = ((uint32_t)ii[k] << 14) | (uint32_t)jg;
            }
        }
    }
    __syncthreads();
    if (tid == 0) {
        int n = min(lcnt, LBUF);
        lcnt = n;
        lbase = atomicAdd(gcnt, n);                     // ONE global atomic per block
    }
    __syncthreads();
    for (int t = tid; t < lcnt; t += BLOCK) {
        int s = lbase + t;
        if (s < ECAP) edges[s] = lbuf[t];
    }
}

__global__ void k_deg_edges(const uint32_t* __restrict__ edges, const int* __restrict__ gcnt,
                            int* __restrict__ deg) {
    int n = min(*gcnt, ECAP);
    for (int e = blockIdx.x * BLOCK + threadIdx.x; e < n; e += gridDim.x * BLOCK) {
        uint32_t p = edges[e];
        atomicAdd(&deg[p >> 14], 1);           // fire-and-forget
        atomicAdd(&deg[p & (N_PTS - 1)], 1);
    }
}

__global__ void k_core(const int* __restrict__ deg, int* __restrict__ core) {
    int i = blockIdx.x * BLOCK + threadIdx.x;
    core[i] = (deg[i] >= MINPTS) ? 1 : 0;
}

__global__ void k_union_edges(const uint32_t* __restrict__ edges, const int* __restrict__ gcnt,
                              const int* __restrict__ core, int* __restrict__ parent) {
    int n = min(*gcnt, ECAP);
    for (int e = blockIdx.x * BLOCK + threadIdx.x; e < n; e += gridDim.x * BLOCK) {
        uint32_t p = edges[e];
        int i = p >> 14, j = p & (N_PTS - 1);
        if (core[i] && core[j]) uf_union(parent, i, j);
    }
}

// comp[i] = find(i); rootmin init: core -> own component root, else sentinel N.
__global__ void k_flatten(int* __restrict__ parent, int* __restrict__ comp,
                          const int* __restrict__ core, int* __restrict__ rootmin) {
    int i = blockIdx.x * BLOCK + threadIdx.x;
    int r = uf_find(parent, i);
    comp[i] = r;
    rootmin[i] = core[i] ? r : N_PTS;
}

// Border points: min component-root over core neighbors. Core-core edges are
// same-component (no-op), so only mixed edges matter.
__global__ void k_rootmin_edges(const uint32_t* __restrict__ edges, const int* __restrict__ gcnt,
                                const int* __restrict__ core, const int* __restrict__ comp,
                                int* __restrict__ rootmin) {
    int n = min(*gcnt, ECAP);
    for (int e = blockIdx.x * BLOCK + threadIdx.x; e < n; e += gridDim.x * BLOCK) {
        uint32_t p = edges[e];
        int i = p >> 14, j = p & (N_PTS - 1);
        int ci = core[i], cj = core[j];
        if (cj && !ci) atomicMin(&rootmin[i], comp[j]);
        else if (ci && !cj) atomicMin(&rootmin[j], comp[i]);
    }
}

// Single block: renumber roots in scan order (two-level scan), emit labels.
__global__ void k_finalize(const int* __restrict__ core, const int* __restrict__ comp,
                           const int* __restrict__ rootmin, int* __restrict__ rank,
                           float* __restrict__ out) {
    __shared__ int partial[1024];
    __shared__ int gbase[64];
    const int tid = threadIdx.x;
    const int CH = N_PTS / 1024;   // 16
    const int base = tid * CH;
    int flags[N_PTS / 1024];
    int s = 0;
#pragma unroll
    for (int k = 0; k < CH; ++k) {
        int i = base + k;
        flags[k] = (core[i] && comp[i] == i) ? 1 : 0;
        s += flags[k];
    }
    partial[tid] = s;
    __syncthreads();
    if (tid < 64) {                 // wave 0: two-level exclusive scan
        int ex = 0;
        for (int r = 0; r < 16; ++r) {
            int t = partial[tid * 16 + r];
            partial[tid * 16 + r] = ex;
            ex += t;
        }
        int inc = ex;
        for (int d = 1; d < 64; d <<= 1) {
            int v = __shfl_up(inc, d, 64);
            if (tid >= d) inc += v;
        }
        gbase[tid] = inc - ex;      // exclusive base of this group of 16
    }
    __syncthreads();
    int acc = gbase[tid >> 4] + partial[tid];   // exclusive prefix at `base`
#pragma unroll
    for (int k = 0; k < CH; ++k) {
        acc += flags[k];
        rank[base + k] = acc - 1;   // inclusive cumsum - 1
    }
    __syncthreads();
#pragma unroll
    for (int k = 0; k < CH; ++k) {
        int i = base + k;
        int rm = rootmin[i];
        out[i] = (rm < N_PTS) ? (float)rank[rm] : -1.0f;
    }
}

extern "C" void kernel_launch(void* const* d_in, const int* in_sizes, int n_in,
                              void* d_out, int out_size, void* d_ws, size_t ws_size,
                              hipStream_t stream) {
    (void)in_sizes; (void)n_in; (void)out_size; (void)ws_size;
    const float* pts = (const float*)d_in[0];
    float* out = (float*)d_out;

    // ws layout: 6 x N 4-byte arrays, counter, edge list (~2.4 MB total)
    float* sq      = (float*)d_ws;
    int*   ibase   = (int*)d_ws;
    int*   deg     = ibase + 1 * N_PTS;
    int*   core    = ibase + 2 * N_PTS;
    int*   parent  = ibase + 3 * N_PTS;
    int*   comp    = ibase + 4 * N_PTS;
    int*   rootmin = ibase + 5 * N_PTS;
    int*   gcnt    = ibase + 6 * N_PTS;
    uint32_t* edges = (uint32_t*)(ibase + 6 * N_PTS + 64);
    int*   rank    = deg;   // deg dead after k_core

    dim3 blk(BLOCK);
    dim3 grid1(N_PTS / BLOCK);     // 64
    dim3 gridT(NT, NT);            // 32 x 32, lower triangle live
    dim3 gridE(512);               // edge-list kernels: 8 waves/SIMD

    k_init<<<grid1, blk, 0, stream>>>(pts, sq, deg, parent, gcnt);
    k_edges<<<gridT, blk, 0, stream>>>(pts, sq, edges, gcnt);
    k_deg_edges<<<gridE, blk, 0, stream>>>(edges, gcnt, deg);
    k_core<<<grid1, blk, 0, stream>>>(deg, core);
    k_union_edges<<<gridE, blk, 0, stream>>>(edges, gcnt, core, parent);
    k_flatten<<<grid1, blk, 0, stream>>>(parent, comp, core, rootmin);
    k_rootmin_edges<<<gridE, blk, 0, stream>>>(edges, gcnt, core, comp, rootmin);
    k_finalize<<<1, 1024, 0, stream>>>(core, comp, rootmin, rank, out);
}

// Round 3
// 277.365 us; speedup vs baseline: 2.7657x; 2.7657x over previous
//
#include <hip/hip_runtime.h>
#include <stdint.h>

// DBSCAN, N=16384 points in R^3, eps=0.2, minPts=10.
//
// R3 structure (3 launches):
//   k_init  : sq, deg=1 (self), rm=N, gcnt=0
//   k_edges : triangular N^2 pass -> compact edge list + fused degree counts
//   k_cc    : ONE 1024-thread block; parent[16384] in LDS (64 KB).
//             Shiloach-Vishkin hook+compress rounds (LDS atomicMin, no CAS
//             retry chains -> avoids R2's 900us device-atomic storm), then
//             border root-min (global fire-and-forget atomicMin), scan-order
//             renumbering, and the final label write -- all fused.
//
// Numerics replicate the reference EXACTLY in fp32 (absmax=0 in R1/R2):
//   sq  = (x*x + y*y) + z*z               (left-to-right)
//   dot = fma(z,z', fma(y,y', x*x'))      (BLAS k-ordered FMA chain)
//   d2  = (sq_i + sq_j) - 2.0f*dot ; adj = d2 < 0.04f

#define N_PTS   16384
#define BLOCK   256
#define IPT     2
#define TILE    512
#define NT      (N_PTS / TILE)      // 32
#define EPS2    0.04f
#define MINPTS  10
#define ECAP    (1 << 19)
#define LBUF    1024
#define NCC     1024                // k_cc block size
#define CHUNK   (N_PTS / NCC)       // 16 nodes per thread
#define F_MIX   0x80000000u         // edge flag: mixed core/non-core (kept for rootmin)
#define F_DEAD  0xC0000000u         // edge flag: dead (merged core-core, or no core)

__device__ __forceinline__ float dist2(float px, float py, float pz, float sqi, float4 q) {
    float dot = __fmaf_rn(pz, q.z, __fmaf_rn(py, q.y, __fmul_rn(px, q.x)));
    return __fsub_rn(__fadd_rn(sqi, q.w), __fmul_rn(2.0f, dot));
}

// ---------------------------------------------------------------------------
__global__ void k_init(const float* __restrict__ pts, float* __restrict__ sq,
                       int* __restrict__ deg, int* __restrict__ rm,
                       int* __restrict__ gcnt) {
    int i = blockIdx.x * BLOCK + threadIdx.x;
    float x = pts[3 * i], y = pts[3 * i + 1], z = pts[3 * i + 2];
    sq[i] = __fadd_rn(__fadd_rn(__fmul_rn(x, x), __fmul_rn(y, y)), __fmul_rn(z, z));
    deg[i] = 1;            // self-neighbor (d=0 < eps)
    rm[i] = N_PTS;         // border root-min sentinel
    if (i == 0) *gcnt = 0;
}

// Triangular N^2: detect eps-pairs (j<i), append packed (i<<14|j), count degrees.
__global__ void k_edges(const float* __restrict__ pts, const float* __restrict__ sq,
                        uint32_t* __restrict__ edges, int* __restrict__ gcnt,
                        int* __restrict__ deg) {
    const int bi = blockIdx.x, bj = blockIdx.y;
    if (bj > bi) return;                        // above diagonal: nothing
    __shared__ float4 sj[TILE];
    __shared__ int sdeg[TILE];
    __shared__ uint32_t lbuf[LBUF];
    __shared__ int lcnt, lbase;
    const int tid = threadIdx.x;
    if (tid == 0) lcnt = 0;
    const int i0 = bi * TILE, j0 = bj * TILE;
    for (int idx = tid; idx < TILE; idx += BLOCK) {
        int j = j0 + idx;
        sj[idx] = make_float4(pts[3 * j], pts[3 * j + 1], pts[3 * j + 2], sq[j]);
        sdeg[idx] = 0;
    }
    __syncthreads();
    float px[IPT], py[IPT], pz[IPT], sqi[IPT];
    int ii[IPT], cnt[IPT];
#pragma unroll
    for (int k = 0; k < IPT; ++k) {
        int i = i0 + k * BLOCK + tid;
        ii[k] = i;
        px[k] = pts[3 * i]; py[k] = pts[3 * i + 1]; pz[k] = pts[3 * i + 2];
        sqi[k] = sq[i]; cnt[k] = 0;
    }
#pragma unroll 4
    for (int j = 0; j < TILE; ++j) {
        float4 q = sj[j];
        int jg = j0 + j;
#pragma unroll
        for (int k = 0; k < IPT; ++k) {
            float d2 = dist2(px[k], py[k], pz[k], sqi[k], q);
            if (d2 < EPS2 && jg < ii[k]) {           // each unordered pair once
                int s = atomicAdd(&lcnt, 1);
                if (s < LBUF) lbuf[s] = ((uint32_t)ii[k] << 14) | (uint32_t)jg;
                ++cnt[k];
                atomicAdd(&sdeg[j], 1);
            }
        }
    }
#pragma unroll
    for (int k = 0; k < IPT; ++k)
        if (cnt[k]) atomicAdd(&deg[ii[k]], cnt[k]);
    __syncthreads();
    for (int idx = tid; idx < TILE; idx += BLOCK)
        if (sdeg[idx]) atomicAdd(&deg[j0 + idx], sdeg[idx]);
    if (tid == 0) {
        int n = min(lcnt, LBUF);
        lcnt = n;
        lbase = atomicAdd(gcnt, n);                 // one global atomic per block
    }
    __syncthreads();
    for (int t = tid; t < lcnt; t += BLOCK) {
        int s = lbase + t;
        if (s < ECAP) edges[s] = lbuf[t];
    }
}

// One block does: core flags, SV connectivity in LDS, border rootmin,
// scan-order renumbering, final labels.
__global__ void __launch_bounds__(NCC)
k_cc(uint32_t* __restrict__ edges, const int* __restrict__ gcnt,
     const int* __restrict__ deg, int* __restrict__ rm,
     int* __restrict__ rank, int* __restrict__ gflag, int* __restrict__ wsum,
     float* __restrict__ out) {
    __shared__ int parent[N_PTS];                   // exactly 64 KB
    const int tid = threadIdx.x;

    // --- phase A: core encoding. core: parent=i (<N). non-core: parent=N+i.
#pragma unroll
    for (int k = 0; k < CHUNK; ++k) {
        int x = k * NCC + tid;                      // coalesced
        parent[x] = (deg[x] >= MINPTS) ? x : (N_PTS + x);
    }
    const int n = min(*gcnt, ECAP);
    __syncthreads();

    // --- phase B: hook + compress rounds (Shiloach-Vishkin)
    for (int r = 0; r < 24; ++r) {
        if (tid == 0) *gflag = 0;
        __syncthreads();
        int ch = 0;
        for (int e = tid; e < n; e += NCC) {
            uint32_t p = edges[e];
            if (p >= F_MIX) continue;               // flagged: nothing to do
            int i = (int)(p >> 14), j = (int)(p & (N_PTS - 1));
            int ri = parent[i], rj = parent[j];
            if (ri >= N_PTS || rj >= N_PTS) {
                // classify once; parent core-status never changes
                edges[e] = p | ((ri >= N_PTS && rj >= N_PTS) ? F_DEAD : F_MIX);
                continue;
            }
            if (ri == rj) { edges[e] = p | F_DEAD; continue; }
            int lo = min(ri, rj), hi = max(ri, rj);
            atomicMin(&parent[hi], lo);             // LDS atomic, fire-and-forget
            ch = 1;
        }
        if (ch) *gflag = 1;                         // same value from all writers
        __syncthreads();
        // compress: every core node jumps to its root (indices only decrease)
#pragma unroll
        for (int k = 0; k < CHUNK; ++k) {
            int x = k * NCC + tid;
            int p0 = parent[x];
            if (p0 < N_PTS) {
                int rt = p0;
                while (true) { int q = parent[rt]; if (q == rt) break; rt = q; }
                parent[x] = rt;
            }
        }
        __syncthreads();
        if (*gflag == 0) break;                     // uniform branch
    }

    // --- phase C: border root-min over mixed edges (global fire-and-forget)
    for (int e = tid; e < n; e += NCC) {
        uint32_t p = edges[e];
        if ((p & F_DEAD) == F_MIX) {
            int i = (int)((p >> 14) & (N_PTS - 1)), j = (int)(p & (N_PTS - 1));
            int ri = parent[i], rj = parent[j];
            if (ri < N_PTS) atomicMin(&rm[j], ri);  // i core, j border
            else            atomicMin(&rm[i], rj);  // j core, i border
        }
    }

    // --- phase D: rank = exclusive count of roots before each root index
    const int base_node = tid * CHUNK;
    int s = 0;
#pragma unroll
    for (int k = 0; k < CHUNK; ++k)
        s += (parent[base_node + k] == base_node + k) ? 1 : 0;
    int lane = tid & 63, wv = tid >> 6;             // 16 waves
    int incl = s;
#pragma unroll
    for (int d = 1; d < 64; d <<= 1) {
        int v = __shfl_up(incl, d, 64);
        if (lane >= d) incl += v;
    }
    if (lane == 63) wsum[wv] = incl;
    __syncthreads();
    int wbase = 0;
    for (int w = 0; w < wv; ++w) wbase += wsum[w];
    int c = wbase + incl - s;                       // exclusive prefix at base_node
#pragma unroll
    for (int k = 0; k < CHUNK; ++k) {
        int x = base_node + k;
        if (parent[x] == x) rank[x] = c++;
    }
    __syncthreads();                                // rank + rm atomics drained

    // --- phase E: labels
#pragma unroll
    for (int k = 0; k < CHUNK; ++k) {
        int x = base_node + k;
        int p0 = parent[x];
        if (p0 < N_PTS) {
            out[x] = (float)rank[p0];               // core: own component
        } else {
            int rv = __hip_atomic_load(&rm[x], __ATOMIC_RELAXED, __HIP_MEMORY_SCOPE_AGENT);
            out[x] = (rv < N_PTS) ? (float)rank[rv] : -1.0f;
        }
    }
}

extern "C" void kernel_launch(void* const* d_in, const int* in_sizes, int n_in,
                              void* d_out, int out_size, void* d_ws, size_t ws_size,
                              hipStream_t stream) {
    (void)in_sizes; (void)n_in; (void)out_size; (void)ws_size;
    const float* pts = (const float*)d_in[0];
    float* out = (float*)d_out;

    float* sq    = (float*)d_ws;
    int*   ibase = (int*)d_ws;
    int*   deg   = ibase + 1 * N_PTS;
    int*   rm    = ibase + 2 * N_PTS;
    int*   rank  = ibase + 3 * N_PTS;
    int*   gcnt  = ibase + 4 * N_PTS;
    int*   gflag = gcnt + 1;
    int*   wsum  = gcnt + 2;                 // 16 words
    uint32_t* edges = (uint32_t*)(ibase + 4 * N_PTS + 64);

    dim3 blk(BLOCK);
    k_init<<<dim3(N_PTS / BLOCK), blk, 0, stream>>>(pts, sq, deg, rm, gcnt);
    k_edges<<<dim3(NT, NT), blk, 0, stream>>>(pts, sq, edges, gcnt, deg);
    k_cc<<<dim3(1), dim3(NCC), 0, stream>>>(edges, gcnt, deg, rm, rank, gflag, wsum, out);
}

// Round 4
// 225.065 us; speedup vs baseline: 3.4084x; 1.2324x over previous
//
#include <hip/hip_runtime.h>
#include <stdint.h>

// DBSCAN, N=16384 points in R^3, eps=0.2, minPts=10.
//
// R4 structure (3 launches):
//   k_init  : sq, deg=1 (self), rm=N, gcnt=0
//   k_edges : packed-triangular N^2 pass -> compact edge list + degree counts
//   k_cc    : ONE 1024-thread block, parent[16384] in LDS.
//             Boruvka/SV rounds with EDGE CONTRACTION: each round scans the
//             current live-edge list (uint4 loads), hooks via LDS atomicMin,
//             and appends surviving edges AS ROOT PAIRS to a ping-pong global
//             buffer (wave-aggregated append). Live count shrinks
//             geometrically -> total scan work ~1.4x one pass (R3 re-scanned
//             all 100k edges every round = 157us latency-bound).
//             Compress uses a wavefront chase (16 independent streams/thread).
//             Mixed core<->border edges split off in round 0; after
//             convergence: border root-min, scan-order renumber, labels.
//
// Numerics replicate the reference EXACTLY in fp32 (absmax=0 in R1-R3):
//   sq  = (x*x + y*y) + z*z               (left-to-right)
//   dot = fma(z,z', fma(y,y', x*x'))      (BLAS k-ordered FMA chain)
//   d2  = (sq_i + sq_j) - 2.0f*dot ; adj = d2 < 0.04f

#define N_PTS   16384
#define BLOCK   256
#define IPT     2
#define TILE    512
#define NT      (N_PTS / TILE)          // 32
#define NTRI    (NT * (NT + 1) / 2)     // 528 lower-triangle tile pairs
#define EPS2    0.04f
#define MINPTS  10
#define ECAP    262144                  // edge buffer capacity (words)
#define MCAP    65536                   // mixed-edge buffer capacity
#define LBUF    1024                    // per-block LDS edge staging in k_edges
#define NCC     1024                    // k_cc block size
#define CHUNK   (N_PTS / NCC)           // 16 nodes per thread
#define BIG     N_PTS                   // non-core parent sentinel

__device__ __forceinline__ float dist2(float px, float py, float pz, float sqi, float4 q) {
    float dot = __fmaf_rn(pz, q.z, __fmaf_rn(py, q.y, __fmul_rn(px, q.x)));
    return __fsub_rn(__fadd_rn(sqi, q.w), __fmul_rn(2.0f, dot));
}

// ---------------------------------------------------------------------------
__global__ void k_init(const float* __restrict__ pts, float* __restrict__ sq,
                       int* __restrict__ deg, int* __restrict__ rm,
                       int* __restrict__ gcnt) {
    int i = blockIdx.x * BLOCK + threadIdx.x;
    float x = pts[3 * i], y = pts[3 * i + 1], z = pts[3 * i + 2];
    sq[i] = __fadd_rn(__fadd_rn(__fmul_rn(x, x), __fmul_rn(y, y)), __fmul_rn(z, z));
    deg[i] = 1;            // self-neighbor (d=0 < eps)
    rm[i] = BIG;           // border root-min sentinel
    if (i == 0) *gcnt = 0;
}

// Packed triangular N^2: detect eps-pairs (j<i), append packed (i<<14|j),
// count degrees. 528 live blocks (R3 launched 1024 with 496 dead -> imbalance).
__global__ void k_edges(const float* __restrict__ pts, const float* __restrict__ sq,
                        uint32_t* __restrict__ edges, int* __restrict__ gcnt,
                        int* __restrict__ deg) {
    // decode blockIdx.x -> (bi, bj), bi >= bj
    int b = blockIdx.x;
    float t = sqrtf(8.0f * (float)b + 1.0f);
    int bi = (int)((t - 1.0f) * 0.5f);
    while ((bi + 1) * (bi + 2) / 2 <= b) ++bi;   // fp round-off fixups
    while (bi * (bi + 1) / 2 > b) --bi;
    int bj = b - bi * (bi + 1) / 2;

    __shared__ float4 sj[TILE];
    __shared__ int sdeg[TILE];
    __shared__ uint32_t lbuf[LBUF];
    __shared__ int lcnt, lbase;
    const int tid = threadIdx.x;
    if (tid == 0) lcnt = 0;
    const int i0 = bi * TILE, j0 = bj * TILE;
    for (int idx = tid; idx < TILE; idx += BLOCK) {
        int j = j0 + idx;
        sj[idx] = make_float4(pts[3 * j], pts[3 * j + 1], pts[3 * j + 2], sq[j]);
        sdeg[idx] = 0;
    }
    __syncthreads();
    float px[IPT], py[IPT], pz[IPT], sqi[IPT];
    int ii[IPT], cnt[IPT];
#pragma unroll
    for (int k = 0; k < IPT; ++k) {
        int i = i0 + k * BLOCK + tid;
        ii[k] = i;
        px[k] = pts[3 * i]; py[k] = pts[3 * i + 1]; pz[k] = pts[3 * i + 2];
        sqi[k] = sq[i]; cnt[k] = 0;
    }
#pragma unroll 4
    for (int j = 0; j < TILE; ++j) {
        float4 q = sj[j];
        int jg = j0 + j;
#pragma unroll
        for (int k = 0; k < IPT; ++k) {
            float d2 = dist2(px[k], py[k], pz[k], sqi[k], q);
            if (d2 < EPS2 && jg < ii[k]) {           // each unordered pair once
                int s = atomicAdd(&lcnt, 1);
                if (s < LBUF) lbuf[s] = ((uint32_t)ii[k] << 14) | (uint32_t)jg;
                ++cnt[k];
                atomicAdd(&sdeg[j], 1);
            }
        }
    }
#pragma unroll
    for (int k = 0; k < IPT; ++k)
        if (cnt[k]) atomicAdd(&deg[ii[k]], cnt[k]);
    __syncthreads();
    for (int idx = tid; idx < TILE; idx += BLOCK)
        if (sdeg[idx]) atomicAdd(&deg[j0 + idx], sdeg[idx]);
    if (tid == 0) {
        int n = min(lcnt, LBUF);
        lcnt = n;
        lbase = atomicAdd(gcnt, n);                  // one global atomic per block
    }
    __syncthreads();
    for (int t2 = tid; t2 < lcnt; t2 += BLOCK) {
        int s = lbase + t2;
        if (s < ECAP) edges[s] = lbuf[t2];
    }
}

// ---------------------------------------------------------------------------
__global__ void __launch_bounds__(NCC)
k_cc(const uint32_t* __restrict__ edges0, const int* __restrict__ gcnt,
     const int* __restrict__ deg, int* __restrict__ rm,
     uint32_t* __restrict__ bufA, uint32_t* __restrict__ bufB,
     uint32_t* __restrict__ mbuf, int* __restrict__ rank,
     float* __restrict__ out) {
    __shared__ int parent[N_PTS];                    // 64 KB
    __shared__ int s_nout, s_nmix;
    __shared__ int wsum[16];
    const int tid = threadIdx.x;
    const int lane = tid & 63;
    const uint64_t lane_lt = (lane == 63) ? ~0ull >> 1 : ((1ull << lane) - 1);

    // --- phase A: parent init. core: self (<N). non-core: BIG sentinel.
#pragma unroll
    for (int k = 0; k < CHUNK; ++k) {
        int x = k * NCC + tid;                       // coalesced deg read
        parent[x] = (deg[x] >= MINPTS) ? x : BIG;
    }
    if (tid == 0) s_nmix = 0;
    __syncthreads();

    int n_in = min(*gcnt, ECAP);
    const uint32_t* cur = edges0;

    // --- phase B: hook + contract rounds
    for (int r = 0; r < 32; ++r) {
        uint32_t* nxt = (r & 1) ? bufB : bufA;
        if (tid == 0) s_nout = 0;
        __syncthreads();
        const bool round0 = (r == 0);
        const int n4 = (n_in + 3) & ~3;
        for (int bb = tid * 4; bb < n4; bb += NCC * 4) {
            uint4 pk = *(const uint4*)(cur + bb);    // 16B load, 4 edges
#pragma unroll
            for (int k = 0; k < 4; ++k) {
                uint32_t p = (k == 0) ? pk.x : (k == 1) ? pk.y : (k == 2) ? pk.z : pk.w;
                bool valid = (bb + k) < n_in;
                int ri = BIG, rj = BIG;
                if (valid) {
                    ri = parent[(int)(p >> 14)];
                    rj = parent[(int)(p & (N_PTS - 1))];
                }
                bool ci = ri < BIG, cj = rj < BIG;
                bool live = valid && ci && cj && (ri != rj);
                int lo = min(ri, rj), hi = max(ri, rj);
                if (live) atomicMin(&parent[hi], lo);    // LDS, fire-and-forget
                // wave-aggregated append of surviving edges AS ROOT PAIRS
                uint64_t mL = __ballot(live);
                if (mL) {
                    int ldr = (int)__ffsll((unsigned long long)mL) - 1;
                    int base = 0;
                    if (lane == ldr) base = atomicAdd(&s_nout, (int)__popcll(mL));
                    base = __shfl(base, ldr);
                    if (live) {
                        int pos = base + (int)__popcll(mL & lane_lt);
                        if (pos < ECAP) nxt[pos] = ((uint32_t)hi << 14) | (uint32_t)lo;
                    }
                }
                if (round0) {                            // split off mixed edges once
                    bool mix = valid && (ci != cj);
                    uint64_t mM = __ballot(mix);
                    if (mM) {
                        int ldr = (int)__ffsll((unsigned long long)mM) - 1;
                        int base = 0;
                        if (lane == ldr) base = atomicAdd(&s_nmix, (int)__popcll(mM));
                        base = __shfl(base, ldr);
                        if (mix) {
                            int pos = base + (int)__popcll(mM & lane_lt);
                            if (pos < MCAP) mbuf[pos] = p;
                        }
                    }
                }
            }
        }
        __syncthreads();
        // compress: wavefront chase, 16 independent streams per thread
        int v[CHUNK];
#pragma unroll
        for (int k = 0; k < CHUNK; ++k) v[k] = parent[k * NCC + tid];
        bool any = true;
        while (any) {
            any = false;
#pragma unroll
            for (int k = 0; k < CHUNK; ++k) {
                if (v[k] < BIG) {
                    int q = parent[v[k]];
                    if (q != v[k]) { v[k] = q; any = true; }
                }
            }
        }
#pragma unroll
        for (int k = 0; k < CHUNK; ++k)
            if (v[k] < BIG) parent[k * NCC + tid] = v[k];
        __syncthreads();
        int nout = s_nout;
        if (nout == 0) break;                        // uniform
        n_in = min(nout, ECAP);
        cur = nxt;
    }

    // --- phase C: border root-min over mixed edges (global fire-and-forget)
    int nm = min(s_nmix, MCAP);
    for (int e = tid; e < nm; e += NCC) {
        uint32_t p = mbuf[e];
        int i = (int)(p >> 14), j = (int)(p & (N_PTS - 1));
        int ri = parent[i], rj = parent[j];
        if (ri < BIG) atomicMin(&rm[j], ri);         // i core, j border
        else          atomicMin(&rm[i], rj);         // j core, i border
    }

    // --- phase D: rank = exclusive count of roots before each root index
    const int base_node = tid * CHUNK;
    int fl[CHUNK];
    int s = 0;
#pragma unroll
    for (int k = 0; k < CHUNK; ++k) {
        fl[k] = (parent[base_node + k] == base_node + k) ? 1 : 0;
        s += fl[k];
    }
    int wv = tid >> 6;                               // 16 waves
    int incl = s;
#pragma unroll
    for (int d = 1; d < 64; d <<= 1) {
        int t = __shfl_up(incl, d, 64);
        if (lane >= d) incl += t;
    }
    if (lane == 63) wsum[wv] = incl;
    __syncthreads();                                 // also drains phase-C atomics
    int wbase = 0;
    for (int w = 0; w < wv; ++w) wbase += wsum[w];
    int c = wbase + incl - s;                        // exclusive prefix at base_node
#pragma unroll
    for (int k = 0; k < CHUNK; ++k)
        if (fl[k]) rank[base_node + k] = c++;
    __syncthreads();

    // --- phase E: labels
#pragma unroll
    for (int k = 0; k < CHUNK; ++k) {
        int x = k * NCC + tid;                       // coalesced out writes
        int p0 = parent[x];
        if (p0 < BIG) {
            out[x] = (float)rank[p0];                // core: own component root
        } else {
            int rv = __hip_atomic_load(&rm[x], __ATOMIC_RELAXED, __HIP_MEMORY_SCOPE_AGENT);
            out[x] = (rv < BIG) ? (float)rank[rv] : -1.0f;
        }
    }
}

extern "C" void kernel_launch(void* const* d_in, const int* in_sizes, int n_in,
                              void* d_out, int out_size, void* d_ws, size_t ws_size,
                              hipStream_t stream) {
    (void)in_sizes; (void)n_in; (void)out_size; (void)ws_size;
    const float* pts = (const float*)d_in[0];
    float* out = (float*)d_out;

    // ws layout (words). All uint4-read buffers 16B-aligned and padded.
    int* ibase = (int*)d_ws;
    float*    sq     = (float*)d_ws;                     // N
    int*      deg    = ibase + 1 * N_PTS;                // N
    int*      rm     = ibase + 2 * N_PTS;                // N
    int*      rank   = ibase + 3 * N_PTS;                // N
    int*      gcnt   = ibase + 4 * N_PTS;                // 64-word block
    uint32_t* edges0 = (uint32_t*)(ibase + 4 * N_PTS + 64);
    uint32_t* bufA   = edges0 + ECAP + 16;
    uint32_t* bufB   = bufA + ECAP + 16;
    uint32_t* mbuf   = bufB + ECAP + 16;                 // + MCAP  (~3.7 MB total)

    dim3 blk(BLOCK);
    k_init<<<dim3(N_PTS / BLOCK), blk, 0, stream>>>(pts, sq, deg, rm, gcnt);
    k_edges<<<dim3(NTRI), blk, 0, stream>>>(pts, sq, edges0, gcnt, deg);
    k_cc<<<dim3(1), dim3(NCC), 0, stream>>>(edges0, gcnt, deg, rm, bufA, bufB,
                                            mbuf, rank, out);
}